// Round 3
// baseline (743.176 us; speedup 1.0000x reference)
//
#include <hip/hip_runtime.h>

typedef unsigned short u16;
typedef unsigned int   u32;
typedef __attribute__((ext_vector_type(8))) short short8;   // 8 x bf16
typedef __attribute__((ext_vector_type(4))) float f32x4;

__device__ __forceinline__ float b2f(u16 u) {
  union { float f; u32 i; } v; v.i = ((u32)u) << 16; return v.f;
}
__device__ __forceinline__ u16 f2b(float f) {
  union { float f; u32 i; } v; v.f = f;
  u32 r = v.i + 0x7fffu + ((v.i >> 16) & 1u);   // RNE
  return (u16)(r >> 16);
}

__device__ __forceinline__ void gload_lds16(const void* g, void* l) {
  __builtin_amdgcn_global_load_lds(
      (const __attribute__((address_space(1))) void*)g,
      (__attribute__((address_space(3))) void*)l, 16, 0, 0);
}

// ---------------- f32 -> bf16 convert (hidden states only) ----------------
__global__ __launch_bounds__(256) void cvt_bf16(const float* __restrict__ in,
                                                u16* __restrict__ out, int n4) {
  for (long i = (long)blockIdx.x * 256 + threadIdx.x; i < n4; i += (long)gridDim.x * 256) {
    const float4 v = ((const float4*)in)[i];
    ushort4 o;
    o.x = f2b(v.x); o.y = f2b(v.y); o.z = f2b(v.z); o.w = f2b(v.w);
    ((ushort4*)out)[i] = o;
  }
}

// ---------------- GEMM: C(MxN) = A(MxK,bf16) * B(NxK,f32)^T ----------------
// Per-wave 128x64 output (0.375 ds_reads/MFMA). Ring-3 LDS, counted vmcnt.
// B is reg-staged from f32 (fused convert, T14); A via global_load_lds.
// Tile BM=NWM*128 x BN=NWN*64, threads=NWM*NWN*64. Requires M%BM==0, N%BN==0,
// K%32==0, K/32>=3, grid=(M/BM)*(N/BN) with grid%8==0.
__device__ __forceinline__ short8 frag_ld(const u16* base, int rbase, int fr, int fq) {
  const int r = rbase + fr;
  return *(const short8*)(base + r * 32 + ((fq ^ ((r >> 1) & 3)) << 3));
}

template <int NWM, int NWN, typename OutT>
__global__ __launch_bounds__(NWM * NWN * 64, 2) void gemm_fb(
    const u16* __restrict__ A, const float* __restrict__ Bf,
    OutT* __restrict__ C, int M, int N, int K) {
  constexpr int NTHR = NWM * NWN * 64;
  constexpr int BM = NWM * 128, BN = NWN * 64;
  constexpr int AE = BM * 32, BE = BN * 32, SLOT = AE + BE;   // u16 counts
  constexpr int LPT_A = (BM * 4) / NTHR;   // 16B chunks per thread (A tile)
  constexpr int LPT_B = (BN * 4) / NTHR;   // 16B chunks per thread (B tile)
  __shared__ u16 lds[3 * SLOT];
  const int tid = threadIdx.x;
  const int wid = tid >> 6, lane = tid & 63;
  const int fr = lane & 15, fq = lane >> 4;
  const int mA = (wid / NWN) * 128, nB = (wid % NWN) * 64;

  // XCD-chunked column-major tile mapping
  const int nty = M / BM;
  const int qx = gridDim.x >> 3;
  const int wg = (blockIdx.x & 7) * qx + (blockIdx.x >> 3);
  const int by = wg % nty, bx = wg / nty;
  const long row0 = (long)by * BM, col0 = (long)bx * BN;

  // staging addresses
  const u16* gA[LPT_A];
  int dA[LPT_A];
#pragma unroll
  for (int i = 0; i < LPT_A; ++i) {
    const int c = tid + i * NTHR, r = c >> 2, j = (c & 3) ^ ((r >> 1) & 3);
    gA[i] = A + (row0 + r) * (long)K + j * 8;
    dA[i] = c * 8;
  }
  int rB[LPT_B], jB[LPT_B], dB[LPT_B];
#pragma unroll
  for (int i = 0; i < LPT_B; ++i) {
    const int c = tid + i * NTHR, r = c >> 2;
    rB[i] = r; jB[i] = ((c & 3) ^ ((r >> 1) & 3)) * 8; dB[i] = AE + c * 8;
  }

  f32x4 acc[8][4];
#pragma unroll
  for (int m = 0; m < 8; ++m)
#pragma unroll
    for (int n = 0; n < 4; ++n) acc[m][n] = f32x4{0.f, 0.f, 0.f, 0.f};

  const int NT = K >> 5;

  // prologue: A(0)->slot0, A(1)->slot1 (async); B(0) via regs -> slot0
#pragma unroll
  for (int i = 0; i < LPT_A; ++i) gload_lds16(gA[i], lds + dA[i]);
#pragma unroll
  for (int i = 0; i < LPT_A; ++i) gload_lds16(gA[i] + 32, lds + SLOT + dA[i]);
  {
    float4 br[LPT_B][2];
#pragma unroll
    for (int i = 0; i < LPT_B; ++i) {
      const float* s = Bf + (col0 + rB[i]) * (long)K + jB[i];
      br[i][0] = *(const float4*)s; br[i][1] = *(const float4*)(s + 4);
    }
    asm volatile("s_waitcnt vmcnt(0)" ::: "memory");
#pragma unroll
    for (int i = 0; i < LPT_B; ++i) {
      short8 v;
      v[0] = (short)f2b(br[i][0].x); v[1] = (short)f2b(br[i][0].y);
      v[2] = (short)f2b(br[i][0].z); v[3] = (short)f2b(br[i][0].w);
      v[4] = (short)f2b(br[i][1].x); v[5] = (short)f2b(br[i][1].y);
      v[6] = (short)f2b(br[i][1].z); v[7] = (short)f2b(br[i][1].w);
      *(short8*)(lds + dB[i]) = v;
    }
  }
  asm volatile("s_waitcnt lgkmcnt(0)" ::: "memory");
  __builtin_amdgcn_s_barrier();

  for (int t = 0; t < NT; ++t) {
    const u16* SA = lds + (t % 3) * SLOT;
    const u16* SB = SA + AE;
    const bool stB = (t + 1) < NT;
    const bool stA = (t + 2) < NT;

    // ---- phase 1: a0-3 + all b; issue B(t+1) f32 loads, then A(t+2) lds ----
    short8 a0 = frag_ld(SA, mA +  0, fr, fq);
    short8 a1 = frag_ld(SA, mA + 16, fr, fq);
    short8 a2 = frag_ld(SA, mA + 32, fr, fq);
    short8 a3 = frag_ld(SA, mA + 48, fr, fq);
    short8 b0 = frag_ld(SB, nB +  0, fr, fq);
    short8 b1 = frag_ld(SB, nB + 16, fr, fq);
    short8 b2 = frag_ld(SB, nB + 32, fr, fq);
    short8 b3 = frag_ld(SB, nB + 48, fr, fq);
    float4 br[LPT_B][2];
    if (stB) {
      const long kb = (long)(t + 1) * 32;
#pragma unroll
      for (int i = 0; i < LPT_B; ++i) {
        const float* s = Bf + (col0 + rB[i]) * (long)K + kb + jB[i];
        br[i][0] = *(const float4*)s; br[i][1] = *(const float4*)(s + 4);
      }
    }
    __builtin_amdgcn_sched_barrier(0);   // keep B-loads ahead of A gload_lds in FIFO
    if (stA) {
      u16* SD = lds + ((t + 2) % 3) * SLOT;
#pragma unroll
      for (int i = 0; i < LPT_A; ++i) gload_lds16(gA[i] + (t + 2) * 32, SD + dA[i]);
    }
    __builtin_amdgcn_s_barrier();
    __builtin_amdgcn_s_setprio(1);
    acc[0][0] = __builtin_amdgcn_mfma_f32_16x16x32_bf16(a0, b0, acc[0][0], 0, 0, 0);
    acc[0][1] = __builtin_amdgcn_mfma_f32_16x16x32_bf16(a0, b1, acc[0][1], 0, 0, 0);
    acc[0][2] = __builtin_amdgcn_mfma_f32_16x16x32_bf16(a0, b2, acc[0][2], 0, 0, 0);
    acc[0][3] = __builtin_amdgcn_mfma_f32_16x16x32_bf16(a0, b3, acc[0][3], 0, 0, 0);
    acc[1][0] = __builtin_amdgcn_mfma_f32_16x16x32_bf16(a1, b0, acc[1][0], 0, 0, 0);
    acc[1][1] = __builtin_amdgcn_mfma_f32_16x16x32_bf16(a1, b1, acc[1][1], 0, 0, 0);
    acc[1][2] = __builtin_amdgcn_mfma_f32_16x16x32_bf16(a1, b2, acc[1][2], 0, 0, 0);
    acc[1][3] = __builtin_amdgcn_mfma_f32_16x16x32_bf16(a1, b3, acc[1][3], 0, 0, 0);
    acc[2][0] = __builtin_amdgcn_mfma_f32_16x16x32_bf16(a2, b0, acc[2][0], 0, 0, 0);
    acc[2][1] = __builtin_amdgcn_mfma_f32_16x16x32_bf16(a2, b1, acc[2][1], 0, 0, 0);
    acc[2][2] = __builtin_amdgcn_mfma_f32_16x16x32_bf16(a2, b2, acc[2][2], 0, 0, 0);
    acc[2][3] = __builtin_amdgcn_mfma_f32_16x16x32_bf16(a2, b3, acc[2][3], 0, 0, 0);
    acc[3][0] = __builtin_amdgcn_mfma_f32_16x16x32_bf16(a3, b0, acc[3][0], 0, 0, 0);
    acc[3][1] = __builtin_amdgcn_mfma_f32_16x16x32_bf16(a3, b1, acc[3][1], 0, 0, 0);
    acc[3][2] = __builtin_amdgcn_mfma_f32_16x16x32_bf16(a3, b2, acc[3][2], 0, 0, 0);
    acc[3][3] = __builtin_amdgcn_mfma_f32_16x16x32_bf16(a3, b3, acc[3][3], 0, 0, 0);
    __builtin_amdgcn_s_setprio(0);
    __builtin_amdgcn_s_barrier();

    // ---- phase 2: a4-7; wait B regs (counted), convert, ds_write B(t+1) ----
    short8 a4 = frag_ld(SA, mA +  64, fr, fq);
    short8 a5 = frag_ld(SA, mA +  80, fr, fq);
    short8 a6 = frag_ld(SA, mA +  96, fr, fq);
    short8 a7 = frag_ld(SA, mA + 112, fr, fq);
    if (stB) {
      if (stA) {
        if constexpr (LPT_A == 2) asm volatile("s_waitcnt vmcnt(2)" ::: "memory");
        else                      asm volatile("s_waitcnt vmcnt(4)" ::: "memory");
      } else {
        asm volatile("s_waitcnt vmcnt(0)" ::: "memory");
      }
      u16* wd = lds + ((t + 1) % 3) * SLOT;
#pragma unroll
      for (int i = 0; i < LPT_B; ++i) {
        short8 v;
        v[0] = (short)f2b(br[i][0].x); v[1] = (short)f2b(br[i][0].y);
        v[2] = (short)f2b(br[i][0].z); v[3] = (short)f2b(br[i][0].w);
        v[4] = (short)f2b(br[i][1].x); v[5] = (short)f2b(br[i][1].y);
        v[6] = (short)f2b(br[i][1].z); v[7] = (short)f2b(br[i][1].w);
        *(short8*)(wd + dB[i]) = v;
      }
    }
    __builtin_amdgcn_s_barrier();
    __builtin_amdgcn_s_setprio(1);
    acc[4][0] = __builtin_amdgcn_mfma_f32_16x16x32_bf16(a4, b0, acc[4][0], 0, 0, 0);
    acc[4][1] = __builtin_amdgcn_mfma_f32_16x16x32_bf16(a4, b1, acc[4][1], 0, 0, 0);
    acc[4][2] = __builtin_amdgcn_mfma_f32_16x16x32_bf16(a4, b2, acc[4][2], 0, 0, 0);
    acc[4][3] = __builtin_amdgcn_mfma_f32_16x16x32_bf16(a4, b3, acc[4][3], 0, 0, 0);
    acc[5][0] = __builtin_amdgcn_mfma_f32_16x16x32_bf16(a5, b0, acc[5][0], 0, 0, 0);
    acc[5][1] = __builtin_amdgcn_mfma_f32_16x16x32_bf16(a5, b1, acc[5][1], 0, 0, 0);
    acc[5][2] = __builtin_amdgcn_mfma_f32_16x16x32_bf16(a5, b2, acc[5][2], 0, 0, 0);
    acc[5][3] = __builtin_amdgcn_mfma_f32_16x16x32_bf16(a5, b3, acc[5][3], 0, 0, 0);
    acc[6][0] = __builtin_amdgcn_mfma_f32_16x16x32_bf16(a6, b0, acc[6][0], 0, 0, 0);
    acc[6][1] = __builtin_amdgcn_mfma_f32_16x16x32_bf16(a6, b1, acc[6][1], 0, 0, 0);
    acc[6][2] = __builtin_amdgcn_mfma_f32_16x16x32_bf16(a6, b2, acc[6][2], 0, 0, 0);
    acc[6][3] = __builtin_amdgcn_mfma_f32_16x16x32_bf16(a6, b3, acc[6][3], 0, 0, 0);
    acc[7][0] = __builtin_amdgcn_mfma_f32_16x16x32_bf16(a7, b0, acc[7][0], 0, 0, 0);
    acc[7][1] = __builtin_amdgcn_mfma_f32_16x16x32_bf16(a7, b1, acc[7][1], 0, 0, 0);
    acc[7][2] = __builtin_amdgcn_mfma_f32_16x16x32_bf16(a7, b2, acc[7][2], 0, 0, 0);
    acc[7][3] = __builtin_amdgcn_mfma_f32_16x16x32_bf16(a7, b3, acc[7][3], 0, 0, 0);
    __builtin_amdgcn_s_setprio(0);
    asm volatile("s_waitcnt lgkmcnt(0)" ::: "memory");   // ds_writes visible
    __builtin_amdgcn_s_barrier();
  }

#pragma unroll
  for (int m = 0; m < 8; ++m)
#pragma unroll
    for (int n = 0; n < 4; ++n)
#pragma unroll
      for (int j = 0; j < 4; ++j) {
        const long r = row0 + mA + m * 16 + fq * 4 + j;
        const long c = col0 + nB + n * 16 + fr;
        if constexpr (sizeof(OutT) == 2) C[r * N + c] = f2b(acc[m][n][j]);
        else                             C[r * N + c] = acc[m][n][j];
      }
}

// ---------------- RoPE in-place on q,k (cols 0..8191 of qkv) ----------------
__global__ __launch_bounds__(256) void rope_qk(u16* __restrict__ qkv,
                                               const float* __restrict__ cosb,
                                               const float* __restrict__ sinb) {
  const int s = blockIdx.x;
  __shared__ u16 row[8192];
  const uint4* src = (const uint4*)(qkv + (long)s * 12288);
  uint4* dst = (uint4*)row;
  for (int i = threadIdx.x; i < 1024; i += 256) dst[i] = src[i];
  __syncthreads();
  const float scale = 0.08838834764831845f;  // 1/sqrt(128)
  for (int i = threadIdx.x; i < 8192; i += 256) {
    const int d = i & 127;
    const int base = i & ~127;
    const float x  = b2f(row[i]);
    const float x2 = b2f(row[base + ((d + 64) & 127)]);
    const float c  = cosb[s * 128 + d];
    const float sn = sinb[s * 128 + d];
    float v = x * c + ((d < 64) ? -x2 : x2) * sn;
    if (i < 4096) v *= scale;                // q only
    qkv[(long)s * 12288 + i] = f2b(v);
  }
}

// ---------------- transpose V: qkv[:,8192+f] (S x 4096) -> vt (4096 x S) ----
__global__ __launch_bounds__(256) void transpose_v(const u16* __restrict__ qkv,
                                                   u16* __restrict__ vt) {
  __shared__ u16 tile[64][72];
  const int f0 = blockIdx.x * 64;
  const int s0 = blockIdx.y * 64;
  const int tid = threadIdx.x;
  const int rr = tid >> 3;
  const int cc = (tid & 7) * 8;
#pragma unroll
  for (int p = 0; p < 2; ++p) {
    const int sr = p * 32 + rr;
    *(uint4*)&tile[sr][cc] =
        *(const uint4*)(qkv + (long)(s0 + sr) * 12288 + 8192 + f0 + cc);
  }
  __syncthreads();
#pragma unroll
  for (int p = 0; p < 2; ++p) {
    const int fr = p * 32 + rr;
    u16 tmp[8];
#pragma unroll
    for (int j = 0; j < 8; ++j) tmp[j] = tile[cc + j][fr];
    *(uint4*)(vt + (long)(f0 + fr) * 2048 + s0 + cc) = *(uint4*)tmp;
  }
}

// ---------------- causal flash attention ------------------------------------
__global__ __launch_bounds__(256) void attn_fwd(const u16* __restrict__ Qb,
                                                const u16* __restrict__ Kb,
                                                const u16* __restrict__ Vt,
                                                u16* __restrict__ Ob) {
  const int h  = blockIdx.y;
  const int q0 = blockIdx.x * 64;
  const int tid = threadIdx.x;
  const int wid = tid >> 6, lane = tid & 63;
  const int fr = lane & 15, fq = lane >> 4;

  __shared__ u16 Ks[64 * 128];
  __shared__ u16 Vts[128 * 64];
  __shared__ u16 Ps[4][16 * 72];

  short8 qf[4];
  {
    const long qrow = q0 + wid * 16 + fr;
#pragma unroll
    for (int kk = 0; kk < 4; ++kk)
      qf[kk] = *(const short8*)(Qb + qrow * 12288 + h * 128 + kk * 32 + fq * 8);
  }

  f32x4 Oacc[8];
#pragma unroll
  for (int f = 0; f < 8; ++f) Oacc[f] = f32x4{0.f, 0.f, 0.f, 0.f};
  float mrun[4], lrun[4];
#pragma unroll
  for (int j = 0; j < 4; ++j) { mrun[j] = -1e30f; lrun[j] = 0.f; }

  const int nt = blockIdx.x + 1;
  for (int t = 0; t < nt; ++t) {
    const int kv0 = t * 64;
#pragma unroll
    for (int i = 0; i < 4; ++i) {
      const int c = wid * 4 + i;
      {
        const int r = c * 4 + (lane >> 4);
        const int p = lane & 15;
        const int jsrc = p ^ (r & 7);
        gload_lds16(Kb + (long)(kv0 + r) * 12288 + h * 128 + jsrc * 8,
                    (char*)Ks + c * 1024);
      }
      {
        const int d = c * 8 + (lane >> 3);
        const int p = lane & 7;
        const int jsrc = p ^ (d & 7);
        gload_lds16(Vt + (long)(h * 128 + d) * 2048 + kv0 + jsrc * 8,
                    (char*)Vts + c * 1024);
      }
    }
    __syncthreads();

    f32x4 S[4];
#pragma unroll
    for (int n = 0; n < 4; ++n) S[n] = f32x4{0.f, 0.f, 0.f, 0.f};
#pragma unroll
    for (int kk = 0; kk < 4; ++kk) {
#pragma unroll
      for (int n = 0; n < 4; ++n) {
        const int r = n * 16 + fr;
        const int p = (kk * 4 + fq) ^ (r & 7);
        short8 kf = *(const short8*)((const char*)Ks + r * 256 + p * 16);
        S[n] = __builtin_amdgcn_mfma_f32_16x16x32_bf16(qf[kk], kf, S[n], 0, 0, 0);
      }
    }

    float P[4][4];
    float tm[4] = {-1e30f, -1e30f, -1e30f, -1e30f};
#pragma unroll
    for (int n = 0; n < 4; ++n) {
      const int kv = kv0 + n * 16 + fr;
#pragma unroll
      for (int j = 0; j < 4; ++j) {
        const int qi = q0 + wid * 16 + fq * 4 + j;
        const float s = (kv <= qi) ? S[n][j] : -1e30f;
        P[n][j] = s;
        tm[j] = fmaxf(tm[j], s);
      }
    }
#pragma unroll
    for (int j = 0; j < 4; ++j)
#pragma unroll
      for (int msk = 1; msk < 16; msk <<= 1)
        tm[j] = fmaxf(tm[j], __shfl_xor(tm[j], msk));

    float al[4], rs[4];
#pragma unroll
    for (int j = 0; j < 4; ++j) {
      const float mn = fmaxf(mrun[j], tm[j]);
      al[j] = __expf(mrun[j] - mn);
      mrun[j] = mn;
      rs[j] = 0.f;
    }
#pragma unroll
    for (int n = 0; n < 4; ++n)
#pragma unroll
      for (int j = 0; j < 4; ++j) {
        const float p = __expf(P[n][j] - mrun[j]);
        P[n][j] = p;
        rs[j] += p;
      }
#pragma unroll
    for (int j = 0; j < 4; ++j) {
#pragma unroll
      for (int msk = 1; msk < 16; msk <<= 1) rs[j] += __shfl_xor(rs[j], msk);
      lrun[j] = lrun[j] * al[j] + rs[j];
    }
#pragma unroll
    for (int f = 0; f < 8; ++f) {
      f32x4 o = Oacc[f];
#pragma unroll
      for (int j = 0; j < 4; ++j) o[j] *= al[j];
      Oacc[f] = o;
    }

#pragma unroll
    for (int n = 0; n < 4; ++n)
#pragma unroll
      for (int j = 0; j < 4; ++j)
        Ps[wid][(fq * 4 + j) * 72 + n * 16 + fr] = f2b(P[n][j]);

#pragma unroll
    for (int kb = 0; kb < 2; ++kb) {
      short8 pa = *(const short8*)(Ps[wid] + fr * 72 + kb * 32 + fq * 8);
#pragma unroll
      for (int f = 0; f < 8; ++f) {
        const int d = f * 16 + fr;
        const int p = (kb * 4 + fq) ^ (d & 7);
        short8 vf = *(const short8*)((const char*)Vts + d * 128 + p * 16);
        Oacc[f] = __builtin_amdgcn_mfma_f32_16x16x32_bf16(pa, vf, Oacc[f], 0, 0, 0);
      }
    }
    __syncthreads();
  }

#pragma unroll
  for (int j = 0; j < 4; ++j) {
    const float inv = 1.f / lrun[j];
    const long r = q0 + wid * 16 + fq * 4 + j;
#pragma unroll
    for (int f = 0; f < 8; ++f)
      Ob[r * 4096 + h * 128 + f * 16 + fr] = f2b(Oacc[f][j] * inv);
  }
}

// ---------------- launch ----------------------------------------------------
extern "C" void kernel_launch(void* const* d_in, const int* in_sizes, int n_in,
                              void* d_out, int out_size, void* d_ws, size_t ws_size,
                              hipStream_t stream) {
  const float* hs   = (const float*)d_in[0];   // (2048, 4096)
  const float* cosb = (const float*)d_in[1];   // (2048, 128)
  const float* sinb = (const float*)d_in[2];   // (2048, 128)
  const float* wp   = (const float*)d_in[3];   // (12288, 4096)
  const float* wo   = (const float*)d_in[4];   // (4096, 4096)
  float* out = (float*)d_out;                  // (2048, 4096)
  char* ws = (char*)d_ws;

  // workspace: h_bf 16MB | qkv 48MB | vt 16MB | attn 16MB  (total 96MB)
  u16* h_bf = (u16*)(ws);
  u16* qkv  = (u16*)(ws + 16777216);
  u16* vt   = (u16*)(ws + 67108864);
  u16* attn = (u16*)(ws + 83886080);

  cvt_bf16<<<2048, 256, 0, stream>>>(hs, h_bf, 8388608 / 4);
  gemm_fb<2, 4, u16><<<384, 512, 0, stream>>>(h_bf, wp, qkv, 2048, 12288, 4096);
  rope_qk<<<2048, 256, 0, stream>>>(qkv, cosb, sinb);
  transpose_v<<<dim3(64, 32), 256, 0, stream>>>(qkv, vt);
  attn_fwd<<<dim3(32, 32), 256, 0, stream>>>(qkv, qkv + 4096, vt, attn);
  gemm_fb<2, 2, float><<<256, 256, 0, stream>>>(attn, wo, out, 2048, 4096, 4096);
}